// Round 9
// baseline (26.570 us; speedup 1.0000x reference)
//
#include <hip/hip_runtime.h>

#define BEV_H 150
#define BEV_W 150
#define NCAM  6
#define CC    128
#define FH    48
#define FW    88
#define IMG_Hf 480.0f
#define IMG_Wf 800.0f
#define NPTS  24
#define NPIX  (NCAM * FH * FW)

__device__ __forceinline__ float rdlanef(float x, int l) {
    return __uint_as_float((unsigned)__builtin_amdgcn_readlane((int)__float_as_uint(x), l));
}
__device__ __forceinline__ float bflo(unsigned x) { return __uint_as_float(x << 16); }
__device__ __forceinline__ float bfhi(unsigned x) { return __uint_as_float(x & 0xffff0000u); }

// ---- feat f32 -> bf16 (RNE) into workspace ----
__global__ __launch_bounds__(256) void conv_bf16_kernel(
    const float* __restrict__ in, unsigned short* __restrict__ out16)
{
    const int i = blockIdx.x * 256 + threadIdx.x;
    const int n4 = NPIX * CC / 4;
    if (i < n4) {
        const float4 v = ((const float4*)in)[i];
        unsigned a = __float_as_uint(v.x), b = __float_as_uint(v.y);
        unsigned c = __float_as_uint(v.z), d = __float_as_uint(v.w);
        a = (a + 0x7fffu + ((a >> 16) & 1u)) >> 16;
        b = (b + 0x7fffu + ((b >> 16) & 1u)) >> 16;
        c = (c + 0x7fffu + ((c >> 16) & 1u)) >> 16;
        d = (d + 0x7fffu + ((d >> 16) & 1u)) >> 16;
        uint2 o; o.x = a | (b << 16); o.y = c | (d << 16);
        ((uint2*)out16)[i] = o;
    }
}

__global__ __launch_bounds__(128) void bev_sample_kernel(
    const unsigned short* __restrict__ feat16,  // (NCAM, FH, FW, C) bf16
    const float* __restrict__ I_,
    const float* __restrict__ E_,
    const float* __restrict__ grid,
    float* __restrict__ out)
{
    const int tid  = threadIdx.x;
    const int lane = tid & 63;
    const int wv   = tid >> 6;
    const int l32  = lane & 31;
    const bool lowhalf = (lane < 32);

    // --- 2D-compact XCD regions (2x4 in 75x75 patch space) ---
    const int r    = blockIdx.x & 7;
    const int i    = blockIdx.x >> 3;
    const int row0 = (r < 4) ? 0 : 38;
    const int nrow = (r < 4) ? 38 : 37;
    const int c3   = r & 3;
    const int col0 = c3 * 19;
    const int wr   = (c3 == 3) ? 18 : 19;
    if (i >= nrow * wr) return;
    int ph, pw;
    if (wr == 19) { ph = i / 19; pw = i - ph * 19; }
    else          { ph = i / 18; pw = i - ph * 18; }
    ph += row0; pw += col0;

    const int h  = ph * 2 + wv;
    const int wA = pw * 2;
    const int qA = h * BEV_W + wA;

    // --- early grid loads ---
    const bool actA = (lane < NPTS);
    const bool actB = (lane >= 32) && (lane < 32 + NPTS);
    float gx = 0.f, gy = 0.f, gz = 0.f;
    int n = 0;
    if (actA || actB) {
        n = l32 >> 2;
        const int d = l32 & 3;
        const int wc = wA + (actB ? 1 : 0);
        gx = grid[((d * 3 + 0) * BEV_H + h) * BEV_W + wc];
        gy = grid[((d * 3 + 1) * BEV_H + h) * BEV_W + wc];
        gz = grid[((d * 3 + 2) * BEV_H + h) * BEV_W + wc];
    }

    // --- cooperative l2i in LDS ---
    __shared__ __align__(16) float s_l2i[NCAM][12];
    if (tid < NCAM * 12) {
        const int nn = tid / 12, rr = tid % 12;
        const int ii = rr >> 2, j = rr & 3;
        float acc = 0.f;
        #pragma unroll
        for (int k = 0; k < 3; ++k)
            acc += I_[nn * 9 + ii * 3 + k] * E_[nn * 16 + k * 4 + j];
        s_l2i[nn][rr] = acc;
    }
    __syncthreads();

    // --- projection: lanes 0-23 = cell A, 32-55 = cell B ---
    int   iT = 0, iB = 0;
    float wTL = 0.f, wTR = 0.f, wBL = 0.f, wBR = 0.f;
    bool  m = false;

    if (actA || actB) {
        const float x = gx * 102.4f - 51.2f;
        const float y = gy * 102.4f - 51.2f;
        const float z = gz * 8.0f   - 5.0f;

        const float4 M0 = *(const float4*)&s_l2i[n][0];
        const float4 M1 = *(const float4*)&s_l2i[n][4];
        const float4 M2 = *(const float4*)&s_l2i[n][8];
        const float p0 = M0.x * x + M0.y * y + M0.z * z + M0.w;
        const float p1 = M1.x * x + M1.y * y + M1.z * z + M1.w;
        const float p2 = M2.x * x + M2.y * y + M2.z * z + M2.w;

        const float eps = 1e-5f;
        const float zc = fmaxf(p2, eps);
        const float u = (p0 / zc) * (1.0f / IMG_Wf);
        const float v = (p1 / zc) * (1.0f / IMG_Hf);
        m = (p2 > eps) && (u > 0.f) && (u < 1.f) && (v > 0.f) && (v < 1.f);

        const float px = u * (float)FW - 0.5f;
        const float py = v * (float)FH - 0.5f;
        const float fx0 = floorf(px), fy0 = floorf(py);
        const int x0 = (int)fx0, y0 = (int)fy0;
        const int x1 = x0 + 1,   y1 = y0 + 1;
        const float wx1 = px - fx0, wy1 = py - fy0;
        const float wx0 = 1.f - wx1, wy0 = 1.f - wy1;

        const bool vx0 = (x0 >= 0) && (x0 < FW);
        const bool vx1 = (x1 >= 0) && (x1 < FW);
        const bool vy0 = (y0 >= 0) && (y0 < FH);
        const bool vy1 = (y1 >= 0) && (y1 < FH);
        const int cx0 = min(max(x0, 0), FW - 1), cx1 = min(max(x1, 0), FW - 1);
        const int cy0 = min(max(y0, 0), FH - 1), cy1 = min(max(y1, 0), FH - 1);

        const float w0v = wx0 * wy0 * ((vx0 && vy0) ? 1.f : 0.f);
        const float w1v = wx1 * wy0 * ((vx1 && vy0) ? 1.f : 0.f);
        const float w2v = wx0 * wy1 * ((vx0 && vy1) ? 1.f : 0.f);
        const float w3v = wx1 * wy1 * ((vx1 && vy1) ? 1.f : 0.f);

        const int bx = min(max(x0, 0), FW - 2);
        wTL = ((cx0 == bx)     ? w0v : 0.f) + ((cx1 == bx)     ? w1v : 0.f);
        wTR = ((cx0 == bx + 1) ? w0v : 0.f) + ((cx1 == bx + 1) ? w1v : 0.f);
        wBL = ((cx0 == bx)     ? w2v : 0.f) + ((cx1 == bx)     ? w3v : 0.f);
        wBR = ((cx0 == bx + 1) ? w2v : 0.f) + ((cx1 == bx + 1) ? w3v : 0.f);

        const int base = n * FH * FW;
        iT = (base + cy0 * FW + bx) * CC;
        iB = (base + cy1 * FW + bx) * CC;
    }

    const unsigned long long bal = __ballot(m);
    unsigned balA = (unsigned)(bal & 0xFFFFFFull);
    unsigned balB = (unsigned)((bal >> 32) & 0xFFFFFFull);
    const float cntA = fmaxf((float)__popc(balA), 1.f);
    const float cntB = fmaxf((float)__popc(balB), 1.f);

    float aAx = 0.f, aAy = 0.f, aAz = 0.f, aAw = 0.f;
    float aBx = 0.f, aBy = 0.f, aBz = 0.f, aBw = 0.f;
    const int loff = 4 * lane;   // element offset: 2 columns x 128 ch span

    while (balA | balB) {
        int eA0 = 0, eA1 = 0, eB0 = 32, eB1 = 32;
        float sA0 = 0.f, sA1 = 0.f, sB0 = 0.f, sB1 = 0.f;
        if (balA) {
            eA0 = __builtin_ctz(balA); balA &= balA - 1; sA0 = 1.f;
            if (balA) { eA1 = __builtin_ctz(balA); balA &= balA - 1; sA1 = 1.f; }
            else eA1 = eA0;
        }
        if (balB) {
            eB0 = 32 + __builtin_ctz(balB); balB &= balB - 1; sB0 = 1.f;
            if (balB) { eB1 = 32 + __builtin_ctz(balB); balB &= balB - 1; sB1 = 1.f; }
            else eB1 = eB0;
        }

        const int jTA0 = __builtin_amdgcn_readlane(iT, eA0), jBA0 = __builtin_amdgcn_readlane(iB, eA0);
        const int jTA1 = __builtin_amdgcn_readlane(iT, eA1), jBA1 = __builtin_amdgcn_readlane(iB, eA1);
        const int jTB0 = __builtin_amdgcn_readlane(iT, eB0), jBB0 = __builtin_amdgcn_readlane(iB, eB0);
        const int jTB1 = __builtin_amdgcn_readlane(iT, eB1), jBB1 = __builtin_amdgcn_readlane(iB, eB1);

        const uint2 dTA0 = *(const uint2*)(feat16 + jTA0 + loff);
        const uint2 dBA0 = *(const uint2*)(feat16 + jBA0 + loff);
        const uint2 dTA1 = *(const uint2*)(feat16 + jTA1 + loff);
        const uint2 dBA1 = *(const uint2*)(feat16 + jBA1 + loff);
        const uint2 dTB0 = *(const uint2*)(feat16 + jTB0 + loff);
        const uint2 dBB0 = *(const uint2*)(feat16 + jBB0 + loff);
        const uint2 dTB1 = *(const uint2*)(feat16 + jTB1 + loff);
        const uint2 dBB1 = *(const uint2*)(feat16 + jBB1 + loff);

        const float wTA0 = sA0 * (lowhalf ? rdlanef(wTL, eA0) : rdlanef(wTR, eA0));
        const float wBA0 = sA0 * (lowhalf ? rdlanef(wBL, eA0) : rdlanef(wBR, eA0));
        const float wTA1 = sA1 * (lowhalf ? rdlanef(wTL, eA1) : rdlanef(wTR, eA1));
        const float wBA1 = sA1 * (lowhalf ? rdlanef(wBL, eA1) : rdlanef(wBR, eA1));
        const float wTB0 = sB0 * (lowhalf ? rdlanef(wTL, eB0) : rdlanef(wTR, eB0));
        const float wBB0 = sB0 * (lowhalf ? rdlanef(wBL, eB0) : rdlanef(wBR, eB0));
        const float wTB1 = sB1 * (lowhalf ? rdlanef(wTL, eB1) : rdlanef(wTR, eB1));
        const float wBB1 = sB1 * (lowhalf ? rdlanef(wBL, eB1) : rdlanef(wBR, eB1));

        aAx += wTA0 * bflo(dTA0.x) + wBA0 * bflo(dBA0.x) + wTA1 * bflo(dTA1.x) + wBA1 * bflo(dBA1.x);
        aAy += wTA0 * bfhi(dTA0.x) + wBA0 * bfhi(dBA0.x) + wTA1 * bfhi(dTA1.x) + wBA1 * bfhi(dBA1.x);
        aAz += wTA0 * bflo(dTA0.y) + wBA0 * bflo(dBA0.y) + wTA1 * bflo(dTA1.y) + wBA1 * bflo(dBA1.y);
        aAw += wTA0 * bfhi(dTA0.y) + wBA0 * bfhi(dBA0.y) + wTA1 * bfhi(dTA1.y) + wBA1 * bfhi(dBA1.y);
        aBx += wTB0 * bflo(dTB0.x) + wBB0 * bflo(dBB0.x) + wTB1 * bflo(dTB1.x) + wBB1 * bflo(dBB1.x);
        aBy += wTB0 * bfhi(dTB0.x) + wBB0 * bfhi(dBB0.x) + wTB1 * bfhi(dTB1.x) + wBB1 * bfhi(dBB1.x);
        aBz += wTB0 * bflo(dTB0.y) + wBB0 * bflo(dBB0.y) + wTB1 * bflo(dTB1.y) + wBB1 * bflo(dBB1.y);
        aBw += wTB0 * bfhi(dTB0.y) + wBB0 * bfhi(dBB0.y) + wTB1 * bfhi(dTB1.y) + wBB1 * bfhi(dBB1.y);
    }

    aAx += __shfl_xor(aAx, 32);  aAy += __shfl_xor(aAy, 32);
    aAz += __shfl_xor(aAz, 32);  aAw += __shfl_xor(aAw, 32);
    aBx += __shfl_xor(aBx, 32);  aBy += __shfl_xor(aBy, 32);
    aBz += __shfl_xor(aBz, 32);  aBw += __shfl_xor(aBw, 32);

    const float inv = lowhalf ? (1.f / cntA) : (1.f / cntB);
    const int   q   = lowhalf ? qA : (qA + 1);
    float4 o;
    o.x = (lowhalf ? aAx : aBx) * inv;
    o.y = (lowhalf ? aAy : aBy) * inv;
    o.z = (lowhalf ? aAz : aBz) * inv;
    o.w = (lowhalf ? aAw : aBw) * inv;
    *(float4*)(out + q * CC + 4 * l32) = o;
}

extern "C" void kernel_launch(void* const* d_in, const int* in_sizes, int n_in,
                              void* d_out, int out_size, void* d_ws, size_t ws_size,
                              hipStream_t stream) {
    const float* feat = (const float*)d_in[0];
    const float* I_   = (const float*)d_in[1];
    const float* E_   = (const float*)d_in[2];
    const float* grid = (const float*)d_in[3];
    float* out        = (float*)d_out;

    unsigned short* f16 = (unsigned short*)d_ws;
    const int n4 = NPIX * CC / 4;
    conv_bf16_kernel<<<(n4 + 255) / 256, 256, 0, stream>>>(feat, f16);
    bev_sample_kernel<<<8 * 722, 128, 0, stream>>>(f16, I_, E_, grid, out);
}

// Round 10
// 18.750 us; speedup vs baseline: 1.4171x; 1.4171x over previous
//
#include <hip/hip_runtime.h>

#define BEV_H 150
#define BEV_W 150
#define NCAM  6
#define CC    128
#define FH    48
#define FW    88
#define IMG_Hf 480.0f
#define IMG_Wf 800.0f
#define NPTS  24

__device__ __forceinline__ float rdlanef(float x, int l) {
    return __uint_as_float((unsigned)__builtin_amdgcn_readlane((int)__float_as_uint(x), l));
}

// lean kernel: <=64 VGPR target -> 8 waves/SIMD residency
__global__ __launch_bounds__(128, 8) void bev_sample_kernel(
    const float* __restrict__ feat,   // (NCAM, FH, FW, C)
    const float* __restrict__ I_,
    const float* __restrict__ E_,
    const float* __restrict__ grid,   // (D, 3, BEV_H, BEV_W)
    float* __restrict__ out)          // (Q, C)
{
    const int tid  = threadIdx.x;
    const int lane = tid & 63;
    const int wv   = tid >> 6;
    const int l32  = lane & 31;
    const bool lowhalf = (lane < 32);

    // --- 2D-compact XCD regions (2x4 in 75x75 patch space) ---
    const int r    = blockIdx.x & 7;
    const int i    = blockIdx.x >> 3;
    const int row0 = (r < 4) ? 0 : 38;
    const int nrow = (r < 4) ? 38 : 37;
    const int c3   = r & 3;
    const int col0 = c3 * 19;
    const int wr   = (c3 == 3) ? 18 : 19;
    if (i >= nrow * wr) return;
    int ph, pw;
    if (wr == 19) { ph = i / 19; pw = i - ph * 19; }
    else          { ph = i / 18; pw = i - ph * 18; }
    ph += row0; pw += col0;

    const int h  = ph * 2 + wv;
    const int wA = pw * 2;
    const int qA = h * BEV_W + wA;

    // --- early grid loads ---
    const bool actA = (lane < NPTS);
    const bool actB = (lane >= 32) && (lane < 32 + NPTS);
    float gx = 0.f, gy = 0.f, gz = 0.f;
    int n = 0;
    if (actA || actB) {
        n = l32 >> 2;
        const int d = l32 & 3;
        const int wc = wA + (actB ? 1 : 0);
        gx = grid[((d * 3 + 0) * BEV_H + h) * BEV_W + wc];
        gy = grid[((d * 3 + 1) * BEV_H + h) * BEV_W + wc];
        gz = grid[((d * 3 + 2) * BEV_H + h) * BEV_W + wc];
    }

    // --- cooperative l2i = I @ E[:3,:] in LDS ---
    __shared__ __align__(16) float s_l2i[NCAM][12];
    if (tid < NCAM * 12) {
        const int nn = tid / 12, rr = tid % 12;
        const int ii = rr >> 2, j = rr & 3;
        float acc = 0.f;
        #pragma unroll
        for (int k = 0; k < 3; ++k)
            acc += I_[nn * 9 + ii * 3 + k] * E_[nn * 16 + k * 4 + j];
        s_l2i[nn][rr] = acc;
    }
    __syncthreads();

    // --- projection: lanes 0-23 = cell A, 32-55 = cell B ---
    int   iT = 0, iB = 0;
    float wTL = 0.f, wTR = 0.f, wBL = 0.f, wBR = 0.f;
    bool  m = false;

    if (actA || actB) {
        const float x = gx * 102.4f - 51.2f;
        const float y = gy * 102.4f - 51.2f;
        const float z = gz * 8.0f   - 5.0f;

        const float4 M0 = *(const float4*)&s_l2i[n][0];
        const float4 M1 = *(const float4*)&s_l2i[n][4];
        const float4 M2 = *(const float4*)&s_l2i[n][8];
        const float p0 = M0.x * x + M0.y * y + M0.z * z + M0.w;
        const float p1 = M1.x * x + M1.y * y + M1.z * z + M1.w;
        const float p2 = M2.x * x + M2.y * y + M2.z * z + M2.w;

        const float eps = 1e-5f;
        const float zc = fmaxf(p2, eps);
        const float u = (p0 / zc) * (1.0f / IMG_Wf);
        const float v = (p1 / zc) * (1.0f / IMG_Hf);
        m = (p2 > eps) && (u > 0.f) && (u < 1.f) && (v > 0.f) && (v < 1.f);

        const float px = u * (float)FW - 0.5f;
        const float py = v * (float)FH - 0.5f;
        const float fx0 = floorf(px), fy0 = floorf(py);
        const int x0 = (int)fx0, y0 = (int)fy0;
        const int x1 = x0 + 1,   y1 = y0 + 1;
        const float wx1 = px - fx0, wy1 = py - fy0;
        const float wx0 = 1.f - wx1, wy0 = 1.f - wy1;

        const bool vx0 = (x0 >= 0) && (x0 < FW);
        const bool vx1 = (x1 >= 0) && (x1 < FW);
        const bool vy0 = (y0 >= 0) && (y0 < FH);
        const bool vy1 = (y1 >= 0) && (y1 < FH);
        const int cx0 = min(max(x0, 0), FW - 1), cx1 = min(max(x1, 0), FW - 1);
        const int cy0 = min(max(y0, 0), FH - 1), cy1 = min(max(y1, 0), FH - 1);

        const float w0v = wx0 * wy0 * ((vx0 && vy0) ? 1.f : 0.f);
        const float w1v = wx1 * wy0 * ((vx1 && vy0) ? 1.f : 0.f);
        const float w2v = wx0 * wy1 * ((vx0 && vy1) ? 1.f : 0.f);
        const float w3v = wx1 * wy1 * ((vx1 && vy1) ? 1.f : 0.f);

        const int bx = min(max(x0, 0), FW - 2);
        wTL = ((cx0 == bx)     ? w0v : 0.f) + ((cx1 == bx)     ? w1v : 0.f);
        wTR = ((cx0 == bx + 1) ? w0v : 0.f) + ((cx1 == bx + 1) ? w1v : 0.f);
        wBL = ((cx0 == bx)     ? w2v : 0.f) + ((cx1 == bx)     ? w3v : 0.f);
        wBR = ((cx0 == bx + 1) ? w2v : 0.f) + ((cx1 == bx + 1) ? w3v : 0.f);

        const int base = n * FH * FW;
        iT = (base + cy0 * FW + bx) * CC;
        iB = (base + cy1 * FW + bx) * CC;
    }

    const unsigned long long bal = __ballot(m);
    unsigned balA = (unsigned)(bal & 0xFFFFFFull);
    unsigned balB = (unsigned)((bal >> 32) & 0xFFFFFFull);
    const float cntA = fmaxf((float)__popc(balA), 1.f);
    const float cntB = fmaxf((float)__popc(balB), 1.f);

    float aAx = 0.f, aAy = 0.f, aAz = 0.f, aAw = 0.f;
    float aBx = 0.f, aBy = 0.f, aBz = 0.f, aBw = 0.f;
    const int loff = 4 * lane;

    // --- 1 entry per cell per trip: 4 float4 in flight, minimal VGPR ---
    while (balA | balB) {
        int eA = 0, eB = 32;
        float sA = 0.f, sB = 0.f;
        if (balA) { eA = __builtin_ctz(balA); balA &= balA - 1; sA = 1.f; }
        if (balB) { eB = 32 + __builtin_ctz(balB); balB &= balB - 1; sB = 1.f; }

        const int jTA = __builtin_amdgcn_readlane(iT, eA);
        const int jBA = __builtin_amdgcn_readlane(iB, eA);
        const int jTB = __builtin_amdgcn_readlane(iT, eB);
        const int jBB = __builtin_amdgcn_readlane(iB, eB);

        const float4 fTA = *(const float4*)(feat + jTA + loff);
        const float4 fBA = *(const float4*)(feat + jBA + loff);
        const float4 fTB = *(const float4*)(feat + jTB + loff);
        const float4 fBB = *(const float4*)(feat + jBB + loff);

        const float wTA = sA * (lowhalf ? rdlanef(wTL, eA) : rdlanef(wTR, eA));
        const float wBA = sA * (lowhalf ? rdlanef(wBL, eA) : rdlanef(wBR, eA));
        const float wTB = sB * (lowhalf ? rdlanef(wTL, eB) : rdlanef(wTR, eB));
        const float wBB = sB * (lowhalf ? rdlanef(wBL, eB) : rdlanef(wBR, eB));

        aAx += wTA * fTA.x + wBA * fBA.x;
        aAy += wTA * fTA.y + wBA * fBA.y;
        aAz += wTA * fTA.z + wBA * fBA.z;
        aAw += wTA * fTA.w + wBA * fBA.w;
        aBx += wTB * fTB.x + wBB * fBB.x;
        aBy += wTB * fTB.y + wBB * fBB.y;
        aBz += wTB * fTB.z + wBB * fBB.z;
        aBw += wTB * fTB.w + wBB * fBB.w;
    }

    aAx += __shfl_xor(aAx, 32);  aAy += __shfl_xor(aAy, 32);
    aAz += __shfl_xor(aAz, 32);  aAw += __shfl_xor(aAw, 32);
    aBx += __shfl_xor(aBx, 32);  aBy += __shfl_xor(aBy, 32);
    aBz += __shfl_xor(aBz, 32);  aBw += __shfl_xor(aBw, 32);

    const float inv = lowhalf ? (1.f / cntA) : (1.f / cntB);
    const int   q   = lowhalf ? qA : (qA + 1);
    float4 o;
    o.x = (lowhalf ? aAx : aBx) * inv;
    o.y = (lowhalf ? aAy : aBy) * inv;
    o.z = (lowhalf ? aAz : aBz) * inv;
    o.w = (lowhalf ? aAw : aBw) * inv;
    *(float4*)(out + q * CC + 4 * l32) = o;
}

extern "C" void kernel_launch(void* const* d_in, const int* in_sizes, int n_in,
                              void* d_out, int out_size, void* d_ws, size_t ws_size,
                              hipStream_t stream) {
    const float* feat = (const float*)d_in[0];
    const float* I_   = (const float*)d_in[1];
    const float* E_   = (const float*)d_in[2];
    const float* grid = (const float*)d_in[3];
    float* out        = (float*)d_out;

    bev_sample_kernel<<<8 * 722, 128, 0, stream>>>(feat, I_, E_, grid, out);
}

// Round 11
// 18.491 us; speedup vs baseline: 1.4369x; 1.0140x over previous
//
#include <hip/hip_runtime.h>

#define BEV_H 150
#define BEV_W 150
#define NCAM  6
#define CC    128
#define FH    48
#define FW    88
#define IMG_Hf 480.0f
#define IMG_Wf 800.0f
#define NPTS  24

__device__ __forceinline__ float rdlanef(float x, int l) {
    return __uint_as_float((unsigned)__builtin_amdgcn_readlane((int)__float_as_uint(x), l));
}

// 2 entries/cell/trip (8 float4 in flight) AND forced 8 waves/SIMD (<=64 VGPR)
__global__ __launch_bounds__(128, 8) void bev_sample_kernel(
    const float* __restrict__ feat,   // (NCAM, FH, FW, C)
    const float* __restrict__ I_,
    const float* __restrict__ E_,
    const float* __restrict__ grid,   // (D, 3, BEV_H, BEV_W)
    float* __restrict__ out)          // (Q, C)
{
    const int tid  = threadIdx.x;
    const int lane = tid & 63;
    const int wv   = tid >> 6;
    const int l32  = lane & 31;
    const bool lowhalf = (lane < 32);

    // --- 2D-compact XCD regions (2x4 in 75x75 patch space) ---
    const int r    = blockIdx.x & 7;
    const int i    = blockIdx.x >> 3;
    const int row0 = (r < 4) ? 0 : 38;
    const int nrow = (r < 4) ? 38 : 37;
    const int c3   = r & 3;
    const int col0 = c3 * 19;
    const int wr   = (c3 == 3) ? 18 : 19;
    if (i >= nrow * wr) return;
    int ph, pw;
    if (wr == 19) { ph = i / 19; pw = i - ph * 19; }
    else          { ph = i / 18; pw = i - ph * 18; }
    ph += row0; pw += col0;

    const int h  = ph * 2 + wv;
    const int wA = pw * 2;
    const int qA = h * BEV_W + wA;

    // --- early grid loads ---
    const bool actA = (lane < NPTS);
    const bool actB = (lane >= 32) && (lane < 32 + NPTS);
    float gx = 0.f, gy = 0.f, gz = 0.f;
    int n = 0;
    if (actA || actB) {
        n = l32 >> 2;
        const int d = l32 & 3;
        const int wc = wA + (actB ? 1 : 0);
        gx = grid[((d * 3 + 0) * BEV_H + h) * BEV_W + wc];
        gy = grid[((d * 3 + 1) * BEV_H + h) * BEV_W + wc];
        gz = grid[((d * 3 + 2) * BEV_H + h) * BEV_W + wc];
    }

    // --- cooperative l2i = I @ E[:3,:] in LDS ---
    __shared__ __align__(16) float s_l2i[NCAM][12];
    if (tid < NCAM * 12) {
        const int nn = tid / 12, rr = tid % 12;
        const int ii = rr >> 2, j = rr & 3;
        float acc = 0.f;
        #pragma unroll
        for (int k = 0; k < 3; ++k)
            acc += I_[nn * 9 + ii * 3 + k] * E_[nn * 16 + k * 4 + j];
        s_l2i[nn][rr] = acc;
    }
    __syncthreads();

    // --- projection: lanes 0-23 = cell A, 32-55 = cell B ---
    int   iT = 0, iB = 0;
    float wTL = 0.f, wTR = 0.f, wBL = 0.f, wBR = 0.f;
    bool  m = false;

    if (actA || actB) {
        const float x = gx * 102.4f - 51.2f;
        const float y = gy * 102.4f - 51.2f;
        const float z = gz * 8.0f   - 5.0f;

        const float4 M0 = *(const float4*)&s_l2i[n][0];
        const float4 M1 = *(const float4*)&s_l2i[n][4];
        const float4 M2 = *(const float4*)&s_l2i[n][8];
        const float p0 = M0.x * x + M0.y * y + M0.z * z + M0.w;
        const float p1 = M1.x * x + M1.y * y + M1.z * z + M1.w;
        const float p2 = M2.x * x + M2.y * y + M2.z * z + M2.w;

        const float eps = 1e-5f;
        const float zc = fmaxf(p2, eps);
        const float u = (p0 / zc) * (1.0f / IMG_Wf);
        const float v = (p1 / zc) * (1.0f / IMG_Hf);
        m = (p2 > eps) && (u > 0.f) && (u < 1.f) && (v > 0.f) && (v < 1.f);

        const float px = u * (float)FW - 0.5f;
        const float py = v * (float)FH - 0.5f;
        const float fx0 = floorf(px), fy0 = floorf(py);
        const int x0 = (int)fx0, y0 = (int)fy0;
        const int x1 = x0 + 1,   y1 = y0 + 1;
        const float wx1 = px - fx0, wy1 = py - fy0;
        const float wx0 = 1.f - wx1, wy0 = 1.f - wy1;

        const bool vx0 = (x0 >= 0) && (x0 < FW);
        const bool vx1 = (x1 >= 0) && (x1 < FW);
        const bool vy0 = (y0 >= 0) && (y0 < FH);
        const bool vy1 = (y1 >= 0) && (y1 < FH);
        const int cx0 = min(max(x0, 0), FW - 1), cx1 = min(max(x1, 0), FW - 1);
        const int cy0 = min(max(y0, 0), FH - 1), cy1 = min(max(y1, 0), FH - 1);

        const float w0v = wx0 * wy0 * ((vx0 && vy0) ? 1.f : 0.f);
        const float w1v = wx1 * wy0 * ((vx1 && vy0) ? 1.f : 0.f);
        const float w2v = wx0 * wy1 * ((vx0 && vy1) ? 1.f : 0.f);
        const float w3v = wx1 * wy1 * ((vx1 && vy1) ? 1.f : 0.f);

        const int bx = min(max(x0, 0), FW - 2);
        wTL = ((cx0 == bx)     ? w0v : 0.f) + ((cx1 == bx)     ? w1v : 0.f);
        wTR = ((cx0 == bx + 1) ? w0v : 0.f) + ((cx1 == bx + 1) ? w1v : 0.f);
        wBL = ((cx0 == bx)     ? w2v : 0.f) + ((cx1 == bx)     ? w3v : 0.f);
        wBR = ((cx0 == bx + 1) ? w2v : 0.f) + ((cx1 == bx + 1) ? w3v : 0.f);

        const int base = n * FH * FW;
        iT = (base + cy0 * FW + bx) * CC;
        iB = (base + cy1 * FW + bx) * CC;
    }

    const unsigned long long bal = __ballot(m);
    unsigned balA = (unsigned)(bal & 0xFFFFFFull);
    unsigned balB = (unsigned)((bal >> 32) & 0xFFFFFFull);
    const float cntA = fmaxf((float)__popc(balA), 1.f);
    const float cntB = fmaxf((float)__popc(balB), 1.f);

    float aAx = 0.f, aAy = 0.f, aAz = 0.f, aAw = 0.f;
    float aBx = 0.f, aBy = 0.f, aBz = 0.f, aBw = 0.f;
    const int loff = 4 * lane;

    while (balA | balB) {
        int eA0 = 0, eA1 = 0, eB0 = 32, eB1 = 32;
        float sA0 = 0.f, sA1 = 0.f, sB0 = 0.f, sB1 = 0.f;
        if (balA) {
            eA0 = __builtin_ctz(balA); balA &= balA - 1; sA0 = 1.f;
            if (balA) { eA1 = __builtin_ctz(balA); balA &= balA - 1; sA1 = 1.f; }
            else eA1 = eA0;
        }
        if (balB) {
            eB0 = 32 + __builtin_ctz(balB); balB &= balB - 1; sB0 = 1.f;
            if (balB) { eB1 = 32 + __builtin_ctz(balB); balB &= balB - 1; sB1 = 1.f; }
            else eB1 = eB0;
        }

        const int jTA0 = __builtin_amdgcn_readlane(iT, eA0), jBA0 = __builtin_amdgcn_readlane(iB, eA0);
        const int jTA1 = __builtin_amdgcn_readlane(iT, eA1), jBA1 = __builtin_amdgcn_readlane(iB, eA1);
        const int jTB0 = __builtin_amdgcn_readlane(iT, eB0), jBB0 = __builtin_amdgcn_readlane(iB, eB0);
        const int jTB1 = __builtin_amdgcn_readlane(iT, eB1), jBB1 = __builtin_amdgcn_readlane(iB, eB1);

        const float4 fTA0 = *(const float4*)(feat + jTA0 + loff);
        const float4 fBA0 = *(const float4*)(feat + jBA0 + loff);
        const float4 fTA1 = *(const float4*)(feat + jTA1 + loff);
        const float4 fBA1 = *(const float4*)(feat + jBA1 + loff);
        const float4 fTB0 = *(const float4*)(feat + jTB0 + loff);
        const float4 fBB0 = *(const float4*)(feat + jBB0 + loff);
        const float4 fTB1 = *(const float4*)(feat + jTB1 + loff);
        const float4 fBB1 = *(const float4*)(feat + jBB1 + loff);

        const float wTA0 = sA0 * (lowhalf ? rdlanef(wTL, eA0) : rdlanef(wTR, eA0));
        const float wBA0 = sA0 * (lowhalf ? rdlanef(wBL, eA0) : rdlanef(wBR, eA0));
        const float wTA1 = sA1 * (lowhalf ? rdlanef(wTL, eA1) : rdlanef(wTR, eA1));
        const float wBA1 = sA1 * (lowhalf ? rdlanef(wBL, eA1) : rdlanef(wBR, eA1));
        const float wTB0 = sB0 * (lowhalf ? rdlanef(wTL, eB0) : rdlanef(wTR, eB0));
        const float wBB0 = sB0 * (lowhalf ? rdlanef(wBL, eB0) : rdlanef(wBR, eB0));
        const float wTB1 = sB1 * (lowhalf ? rdlanef(wTL, eB1) : rdlanef(wTR, eB1));
        const float wBB1 = sB1 * (lowhalf ? rdlanef(wBL, eB1) : rdlanef(wBR, eB1));

        aAx += wTA0 * fTA0.x + wBA0 * fBA0.x + wTA1 * fTA1.x + wBA1 * fBA1.x;
        aAy += wTA0 * fTA0.y + wBA0 * fBA0.y + wTA1 * fTA1.y + wBA1 * fBA1.y;
        aAz += wTA0 * fTA0.z + wBA0 * fBA0.z + wTA1 * fTA1.z + wBA1 * fBA1.z;
        aAw += wTA0 * fTA0.w + wBA0 * fBA0.w + wTA1 * fTA1.w + wBA1 * fBA1.w;
        aBx += wTB0 * fTB0.x + wBB0 * fBB0.x + wTB1 * fTB1.x + wBB1 * fBB1.x;
        aBy += wTB0 * fTB0.y + wBB0 * fBB0.y + wTB1 * fTB1.y + wBB1 * fBB1.y;
        aBz += wTB0 * fTB0.z + wBB0 * fBB0.z + wTB1 * fTB1.z + wBB1 * fBB1.z;
        aBw += wTB0 * fTB0.w + wBB0 * fBB0.w + wTB1 * fTB1.w + wBB1 * fBB1.w;
    }

    aAx += __shfl_xor(aAx, 32);  aAy += __shfl_xor(aAy, 32);
    aAz += __shfl_xor(aAz, 32);  aAw += __shfl_xor(aAw, 32);
    aBx += __shfl_xor(aBx, 32);  aBy += __shfl_xor(aBy, 32);
    aBz += __shfl_xor(aBz, 32);  aBw += __shfl_xor(aBw, 32);

    const float inv = lowhalf ? (1.f / cntA) : (1.f / cntB);
    const int   q   = lowhalf ? qA : (qA + 1);
    float4 o;
    o.x = (lowhalf ? aAx : aBx) * inv;
    o.y = (lowhalf ? aAy : aBy) * inv;
    o.z = (lowhalf ? aAz : aBz) * inv;
    o.w = (lowhalf ? aAw : aBw) * inv;
    *(float4*)(out + q * CC + 4 * l32) = o;
}

extern "C" void kernel_launch(void* const* d_in, const int* in_sizes, int n_in,
                              void* d_out, int out_size, void* d_ws, size_t ws_size,
                              hipStream_t stream) {
    const float* feat = (const float*)d_in[0];
    const float* I_   = (const float*)d_in[1];
    const float* E_   = (const float*)d_in[2];
    const float* grid = (const float*)d_in[3];
    float* out        = (float*)d_out;

    bev_sample_kernel<<<8 * 722, 128, 0, stream>>>(feat, I_, E_, grid, out);
}